// Round 1
// baseline (75.966 us; speedup 1.0000x reference)
//
#include <hip/hip_runtime.h>
#include <float.h>

#define NBINS 313
#define HW    65536      // 256*256
#define NB    4          // batch
#define NPIX  (NB * HW)  // 262144
#define HALF  (NPIX / 2) // 131072

// Kernel 1: per-pixel NN weight + weighted L2, block partial sums -> d_ws
__global__ __launch_bounds__(256) void loss_main(
    const float* __restrict__ input, const float* __restrict__ target,
    const float* __restrict__ ab, const float* __restrict__ prior,
    float* __restrict__ partials)
{
    __shared__ float4 s_bins[NBINS];
    const int tid = threadIdx.x;

    // Stage bin table: {gx, gy, 0.5*|g|^2, weight}
    for (int i = tid; i < NBINS; i += 256) {
        float gx = ab[2 * i];
        float gy = ab[2 * i + 1];
        s_bins[i] = make_float4(gx, gy, 0.5f * (gx * gx + gy * gy), prior[i]);
    }
    __syncthreads();

    // Two pixels per thread: p0 in first half, p1 in second half (coalesced)
    const int p0 = blockIdx.x * 256 + tid;
    const int p1 = p0 + HALF;

    // pixel p -> flat idx of channel0: (b*2)*HW + n = p + (p & ~(HW-1))
    const int i00 = p0 + (p0 & ~(HW - 1));
    const int i01 = i00 + HW;
    const int i10 = p1 + (p1 & ~(HW - 1));
    const int i11 = i10 + HW;

    const float tx0 = target[i00], ty0 = target[i01];
    const float tx1 = target[i10], ty1 = target[i11];
    const float ax0 = input[i00],  ay0 = input[i01];
    const float ax1 = input[i10],  ay1 = input[i11];

    const float dx0 = ax0 - tx0, dy0 = ay0 - ty0;
    const float dx1 = ax1 - tx1, dy1 = ay1 - ty1;
    const float d2_0 = dx0 * dx0 + dy0 * dy0;
    const float d2_1 = dx1 * dx1 + dy1 * dy1;

    // argmin over bins of (0.5*|g|^2 - g.t)  == argmin of squared distance
    float bf0 = FLT_MAX, bw0 = 0.0f;
    float bf1 = FLT_MAX, bw1 = 0.0f;
    for (int q = 0; q < NBINS; ++q) {
        const float4 bn = s_bins[q];
        const float f0 = fmaf(-bn.x, tx0, fmaf(-bn.y, ty0, bn.z));
        const float f1 = fmaf(-bn.x, tx1, fmaf(-bn.y, ty1, bn.z));
        const bool c0 = f0 < bf0;
        const bool c1 = f1 < bf1;
        bf0 = c0 ? f0 : bf0;  bw0 = c0 ? bn.w : bw0;
        bf1 = c1 ? f1 : bf1;  bw1 = c1 ? bn.w : bw1;
    }

    float sum = d2_0 * bw0 + d2_1 * bw1;

    // wave (64) reduce, then cross-wave via LDS
    for (int off = 32; off > 0; off >>= 1)
        sum += __shfl_down(sum, off);

    __shared__ float s_part[4];
    if ((tid & 63) == 0) s_part[tid >> 6] = sum;
    __syncthreads();
    if (tid == 0)
        partials[blockIdx.x] = s_part[0] + s_part[1] + s_part[2] + s_part[3];
}

// Kernel 2: reduce 512 partials -> scalar loss (mean over batch: *0.25)
__global__ __launch_bounds__(64) void loss_reduce(
    const float* __restrict__ partials, float* __restrict__ out)
{
    const int tid = threadIdx.x;
    float s = 0.0f;
    for (int i = tid; i < 512; i += 64) s += partials[i];
    for (int off = 32; off > 0; off >>= 1)
        s += __shfl_down(s, off);
    if (tid == 0) out[0] = 0.25f * s;
}

extern "C" void kernel_launch(void* const* d_in, const int* in_sizes, int n_in,
                              void* d_out, int out_size, void* d_ws, size_t ws_size,
                              hipStream_t stream)
{
    const float* input  = (const float*)d_in[0];
    const float* target = (const float*)d_in[1];
    const float* ab     = (const float*)d_in[2];
    const float* prior  = (const float*)d_in[3];
    float* out      = (float*)d_out;
    float* partials = (float*)d_ws;

    loss_main<<<HALF / 256, 256, 0, stream>>>(input, target, ab, prior, partials);
    loss_reduce<<<1, 64, 0, stream>>>(partials, out);
}